// Round 1
// baseline (881.767 us; speedup 1.0000x reference)
//
#include <hip/hip_runtime.h>

typedef __bf16 bf16_t;
typedef bf16_t bf16x8 __attribute__((ext_vector_type(8)));
typedef bf16_t bf16x4 __attribute__((ext_vector_type(4)));
typedef float  f32x4  __attribute__((ext_vector_type(4)));

#define NWIN 4096
#define CDIM 256
#define NTOK 64
#define NH   8
#define HDIM 32

// LDS layout (bytes):
//  q:  [8][64][40] bf16 = 40960   (per-wave P scratch reuses own head's region)
//  k:  [8][64][40] bf16 = 40960   (o_lds [64][264] bf16 = 33792 reuses this after PV)
//  v:  [8][32][72] bf16 = 36864
//  xs: [64][264]  bf16 = 33792    (mask f32 [64][64] = 16384 reuses after GEMM1)
#define OFF_Q 0
#define OFF_K 40960
#define OFF_V 81920
#define OFF_X 118784
#define LDS_BYTES 152576

__device__ __forceinline__ f32x4 mfma16(bf16x8 a, bf16x8 b, f32x4 c) {
    return __builtin_amdgcn_mfma_f32_16x16x32_bf16(a, b, c, 0, 0, 0);
}

template<bool USE_WS>
__launch_bounds__(512, 2)
__global__ void win_attn_kernel(const float* __restrict__ x,
                                const float* __restrict__ mask,
                                const float* __restrict__ qkv_w,
                                const float* __restrict__ qkv_b,
                                const float* __restrict__ proj_w,
                                const float* __restrict__ proj_b,
                                const float* __restrict__ bias_table,
                                const bf16_t* __restrict__ qkv_wb,
                                const bf16_t* __restrict__ proj_wb,
                                float* __restrict__ out)
{
    __shared__ __attribute__((aligned(16))) unsigned char smem[LDS_BYTES];
    bf16_t* q_lds    = (bf16_t*)(smem + OFF_Q);
    bf16_t* k_lds    = (bf16_t*)(smem + OFF_K);
    bf16_t* v_lds    = (bf16_t*)(smem + OFF_V);
    bf16_t* xs       = (bf16_t*)(smem + OFF_X);
    float*  mask_lds = (float*) (smem + OFF_X);
    bf16_t* o_lds    = (bf16_t*)(smem + OFF_K);

    const int b    = blockIdx.x;
    const int tid  = threadIdx.x;
    const int w    = tid >> 6;       // wave id 0..7
    const int lane = tid & 63;
    const int quad = lane >> 4;
    const int l15  = lane & 15;

    // ---- Phase 1: stage x[b] (256x64 f32, [c][n]) -> xs[token][c] bf16 (row pad 264)
    {
        const float* xb = x + (size_t)b * (CDIM * NTOK);
        #pragma unroll
        for (int it = 0; it < 8; ++it) {
            int i  = (tid + it * 512) * 4;     // linear idx into [c][n]
            int c  = i >> 6;
            int n0 = i & 63;
            f32x4 v4 = *(const f32x4*)(xb + i);
            #pragma unroll
            for (int j = 0; j < 4; ++j)
                xs[(n0 + j) * 264 + c] = (bf16_t)v4[j];
        }
    }
    __syncthreads();

    // ---- Phase 2: QKV = qkv_w(768x256) @ x(256x64) + qkv_b; wave w -> rows [w*96, w*96+96)
    {
        f32x4 acc[6][4];
        #pragma unroll
        for (int rt = 0; rt < 6; ++rt)
            #pragma unroll
            for (int ct = 0; ct < 4; ++ct)
                acc[rt][ct] = (f32x4){0.f, 0.f, 0.f, 0.f};

        const int row_base = w * 96;
        for (int kk = 0; kk < 8; ++kk) {
            const int c0 = kk * 32;
            bf16x8 afr[6];
            #pragma unroll
            for (int rt = 0; rt < 6; ++rt) {
                int row = row_base + rt * 16 + l15;
                if constexpr (USE_WS) {
                    afr[rt] = *(const bf16x8*)(qkv_wb + row * CDIM + c0 + quad * 8);
                } else {
                    const float* ap = qkv_w + row * CDIM + c0 + quad * 8;
                    f32x4 a0 = *(const f32x4*)ap;
                    f32x4 a1 = *(const f32x4*)(ap + 4);
                    bf16x8 t;
                    #pragma unroll
                    for (int j = 0; j < 4; ++j) { t[j] = (bf16_t)a0[j]; t[j + 4] = (bf16_t)a1[j]; }
                    afr[rt] = t;
                }
            }
            bf16x8 bfr[4];
            #pragma unroll
            for (int ct = 0; ct < 4; ++ct)
                bfr[ct] = *(const bf16x8*)(xs + (ct * 16 + l15) * 264 + c0 + quad * 8);
            #pragma unroll
            for (int rt = 0; rt < 6; ++rt)
                #pragma unroll
                for (int ct = 0; ct < 4; ++ct)
                    acc[rt][ct] = mfma16(afr[rt], bfr[ct], acc[rt][ct]);
        }
        // epilogue: +qkv_b, scatter to q/k/v LDS
        #pragma unroll
        for (int rt = 0; rt < 6; ++rt) {
            int r0  = row_base + rt * 16;
            int rq  = r0 + quad * 4;                 // first of this lane's 4 rows
            f32x4 b4 = *(const f32x4*)(qkv_b + rq);
            int sec = r0 >> 8;                       // 0=q 1=k 2=v
            int h   = (r0 & 255) >> 5;
            int dd0 = rq & 31;
            #pragma unroll
            for (int ct = 0; ct < 4; ++ct) {
                int n = ct * 16 + l15;
                if (sec == 2) {
                    bf16_t* dst = v_lds + h * (32 * 72) + n;
                    #pragma unroll
                    for (int r = 0; r < 4; ++r)
                        dst[(dd0 + r) * 72] = (bf16_t)(acc[rt][ct][r] + b4[r]);
                } else {
                    bf16_t* dst = (sec == 0 ? q_lds : k_lds) + h * (64 * 40) + n * 40 + dd0;
                    bf16x4 pk;
                    #pragma unroll
                    for (int r = 0; r < 4; ++r) pk[r] = (bf16_t)(acc[rt][ct][r] + b4[r]);
                    *(bf16x4*)dst = pk;
                }
            }
        }
    }
    __syncthreads();

    // ---- Phase 3: stage mask[b] into LDS (f32, overwrites xs), then S = (Q^T K) per head
    {
        const float* mb = mask + (size_t)b * (NTOK * NTOK);
        #pragma unroll
        for (int it = 0; it < 2; ++it) {
            int i = (tid + it * 512) * 4;
            *(f32x4*)(mask_lds + i) = *(const f32x4*)(mb + i);
        }
    }

    const int h = w;   // wave = head
    f32x4 sacc[4][4];
    #pragma unroll
    for (int rt = 0; rt < 4; ++rt)
        #pragma unroll
        for (int ct = 0; ct < 4; ++ct)
            sacc[rt][ct] = (f32x4){0.f, 0.f, 0.f, 0.f};
    {
        bf16x8 qa[4], kb[4];
        #pragma unroll
        for (int rt = 0; rt < 4; ++rt)
            qa[rt] = *(const bf16x8*)(q_lds + h * 2560 + (rt * 16 + l15) * 40 + quad * 8);
        #pragma unroll
        for (int ct = 0; ct < 4; ++ct)
            kb[ct] = *(const bf16x8*)(k_lds + h * 2560 + (ct * 16 + l15) * 40 + quad * 8);
        #pragma unroll
        for (int rt = 0; rt < 4; ++rt)
            #pragma unroll
            for (int ct = 0; ct < 4; ++ct)
                sacc[rt][ct] = mfma16(qa[rt], kb[ct], sacc[rt][ct]);
    }
    __syncthreads();   // mask ready for all waves

    // ---- Phase 4: bias + mask + softmax (rows n = rt*16+quad*4+reg; cols m = ct*16+l15)
    {
        const float scale = 0.17677669529663687f;
        int mh[4], mw[4], mcol[4];
        #pragma unroll
        for (int ct = 0; ct < 4; ++ct) {
            int m = ct * 16 + l15;
            mcol[ct] = m; mh[ct] = m >> 3; mw[ct] = m & 7;
        }
        #pragma unroll
        for (int rt = 0; rt < 4; ++rt) {
            #pragma unroll
            for (int reg = 0; reg < 4; ++reg) {
                int n  = rt * 16 + quad * 4 + reg;
                int nh = n >> 3, nw = n & 7;
                float l[4];
                #pragma unroll
                for (int ct = 0; ct < 4; ++ct) {
                    int idx = (nh - mh[ct] + 7) * 15 + (nw - mw[ct] + 7);
                    float bias = bias_table[idx * NH + h];
                    l[ct] = sacc[rt][ct][reg] * scale + bias + mask_lds[n * 64 + mcol[ct]];
                }
                float mx = fmaxf(fmaxf(l[0], l[1]), fmaxf(l[2], l[3]));
                #pragma unroll
                for (int d = 1; d < 16; d <<= 1) mx = fmaxf(mx, __shfl_xor(mx, d, 64));
                float s = 0.f;
                #pragma unroll
                for (int ct = 0; ct < 4; ++ct) { l[ct] = __expf(l[ct] - mx); s += l[ct]; }
                #pragma unroll
                for (int d = 1; d < 16; d <<= 1) s += __shfl_xor(s, d, 64);
                float inv = 1.0f / s;
                #pragma unroll
                for (int ct = 0; ct < 4; ++ct) sacc[rt][ct][reg] = l[ct] * inv;
            }
        }
    }

    // ---- Phase 5: O = P @ V^T per head; P round-trips through own head's q region
    f32x4 oacc[4][2];
    #pragma unroll
    for (int rt = 0; rt < 4; ++rt)
        #pragma unroll
        for (int cd = 0; cd < 2; ++cd)
            oacc[rt][cd] = (f32x4){0.f, 0.f, 0.f, 0.f};
    {
        bf16_t* p_lds = q_lds + h * 2560;   // [64][40]
        #pragma unroll
        for (int ch = 0; ch < 2; ++ch) {
            #pragma unroll
            for (int rt = 0; rt < 4; ++rt)
                #pragma unroll
                for (int reg = 0; reg < 4; ++reg) {
                    int n = rt * 16 + quad * 4 + reg;
                    p_lds[n * 40 + l15]      = (bf16_t)sacc[rt][2 * ch][reg];
                    p_lds[n * 40 + 16 + l15] = (bf16_t)sacc[rt][2 * ch + 1][reg];
                }
            #pragma unroll
            for (int rt = 0; rt < 4; ++rt) {
                bf16x8 pa = *(const bf16x8*)(p_lds + (rt * 16 + l15) * 40 + quad * 8);
                #pragma unroll
                for (int cd = 0; cd < 2; ++cd) {
                    bf16x8 vb = *(const bf16x8*)(v_lds + h * 2304 + (cd * 16 + l15) * 72 + ch * 32 + quad * 8);
                    oacc[rt][cd] = mfma16(pa, vb, oacc[rt][cd]);
                }
            }
        }
    }
    __syncthreads();   // all waves done reading k/v before o_lds overlays k

    // ---- Phase 6: O -> o_lds[token][c] bf16 (row pad 264), c = h*32 + d
    #pragma unroll
    for (int rt = 0; rt < 4; ++rt)
        #pragma unroll
        for (int cd = 0; cd < 2; ++cd) {
            int c = h * 32 + cd * 16 + l15;
            #pragma unroll
            for (int reg = 0; reg < 4; ++reg) {
                int n = rt * 16 + quad * 4 + reg;
                o_lds[n * 264 + c] = (bf16_t)oacc[rt][cd][reg];
            }
        }
    __syncthreads();

    // ---- Phase 7: Y^T[e][n] = proj_w(e,:) . O(n,:); wave w -> e in [w*32, w*32+32)
    {
        f32x4 yacc[2][4];
        #pragma unroll
        for (int rt = 0; rt < 2; ++rt)
            #pragma unroll
            for (int ct = 0; ct < 4; ++ct)
                yacc[rt][ct] = (f32x4){0.f, 0.f, 0.f, 0.f};

        for (int kk = 0; kk < 8; ++kk) {
            const int c0 = kk * 32;
            bf16x8 afr[2];
            #pragma unroll
            for (int rt = 0; rt < 2; ++rt) {
                int e = w * 32 + rt * 16 + l15;
                if constexpr (USE_WS) {
                    afr[rt] = *(const bf16x8*)(proj_wb + e * CDIM + c0 + quad * 8);
                } else {
                    const float* ap = proj_w + e * CDIM + c0 + quad * 8;
                    f32x4 a0 = *(const f32x4*)ap;
                    f32x4 a1 = *(const f32x4*)(ap + 4);
                    bf16x8 t;
                    #pragma unroll
                    for (int j = 0; j < 4; ++j) { t[j] = (bf16_t)a0[j]; t[j + 4] = (bf16_t)a1[j]; }
                    afr[rt] = t;
                }
            }
            bf16x8 bfr[4];
            #pragma unroll
            for (int ct = 0; ct < 4; ++ct)
                bfr[ct] = *(const bf16x8*)(o_lds + (ct * 16 + l15) * 264 + c0 + quad * 8);
            #pragma unroll
            for (int rt = 0; rt < 2; ++rt)
                #pragma unroll
                for (int ct = 0; ct < 4; ++ct)
                    yacc[rt][ct] = mfma16(afr[rt], bfr[ct], yacc[rt][ct]);
        }
        // epilogue: +proj_b, coalesced float4 stores (lane holds 4 consecutive e at fixed token)
        float* ob = out + (size_t)b * (NTOK * CDIM);
        #pragma unroll
        for (int rt = 0; rt < 2; ++rt) {
            int e0 = w * 32 + rt * 16 + quad * 4;
            f32x4 pb4 = *(const f32x4*)(proj_b + e0);
            #pragma unroll
            for (int ct = 0; ct < 4; ++ct) {
                int n = ct * 16 + l15;
                f32x4 r = yacc[rt][ct] + pb4;
                *(f32x4*)(ob + n * 256 + e0) = r;
            }
        }
    }
}

// Convert fp32 weights to bf16 once per launch (into workspace).
__global__ void cvt_weights(const float* __restrict__ qkv_w,
                            const float* __restrict__ proj_w,
                            bf16_t* __restrict__ qkv_wb,
                            bf16_t* __restrict__ proj_wb)
{
    int i = blockIdx.x * 256 + threadIdx.x;
    int base = i * 4;
    const float* src; bf16_t* dst;
    if (base < 196608) { src = qkv_w + base; dst = qkv_wb + base; }
    else { base -= 196608; src = proj_w + base; dst = proj_wb + base; }
    f32x4 v = *(const f32x4*)src;
    bf16x4 o;
    #pragma unroll
    for (int j = 0; j < 4; ++j) o[j] = (bf16_t)v[j];
    *(bf16x4*)dst = o;
}

extern "C" void kernel_launch(void* const* d_in, const int* in_sizes, int n_in,
                              void* d_out, int out_size, void* d_ws, size_t ws_size,
                              hipStream_t stream) {
    const float* x          = (const float*)d_in[0];
    const float* mask       = (const float*)d_in[1];
    const float* qkv_w      = (const float*)d_in[2];
    const float* qkv_b      = (const float*)d_in[3];
    const float* proj_w     = (const float*)d_in[4];
    const float* proj_b     = (const float*)d_in[5];
    const float* bias_table = (const float*)d_in[6];
    float* out = (float*)d_out;

    const size_t ws_needed = (size_t)(196608 + 65536) * sizeof(bf16_t);  // 524288 B
    if (ws_size >= ws_needed) {
        bf16_t* qkv_wb  = (bf16_t*)d_ws;
        bf16_t* proj_wb = qkv_wb + 196608;
        cvt_weights<<<256, 256, 0, stream>>>(qkv_w, proj_w, qkv_wb, proj_wb);
        win_attn_kernel<true><<<NWIN, 512, 0, stream>>>(
            x, mask, qkv_w, qkv_b, proj_w, proj_b, bias_table, qkv_wb, proj_wb, out);
    } else {
        win_attn_kernel<false><<<NWIN, 512, 0, stream>>>(
            x, mask, qkv_w, qkv_b, proj_w, proj_b, bias_table, nullptr, nullptr, out);
    }
}